// Round 2
// baseline (934.977 us; speedup 1.0000x reference)
//
#include <hip/hip_runtime.h>

typedef unsigned short u16;
typedef __attribute__((ext_vector_type(8))) short bf16x8;   // 8 bf16 (bit pattern), 4 VGPRs
typedef __attribute__((ext_vector_type(4))) float f32x4;

#define DEV __device__ __forceinline__

DEV u16 f2bf(float f) {
  union { float f; unsigned u; } v; v.f = f;
  unsigned r = v.u + 0x7fffu + ((v.u >> 16) & 1u);
  return (u16)(r >> 16);
}
DEV float bf2f(u16 h) {
  union { unsigned u; float f; } v; v.u = ((unsigned)h) << 16;
  return v.f;
}
DEV f32x4 mfma16(bf16x8 a, bf16x8 b, f32x4 c) {
  return __builtin_amdgcn_mfma_f32_16x16x32_bf16(a, b, c, 0, 0, 0);
}
DEV void cp16(const u16* g, u16* l) {
  __builtin_amdgcn_global_load_lds((__attribute__((address_space(1))) void*)g,
                                   (__attribute__((address_space(3))) void*)l, 16, 0, 0);
}

// ---------------- split x (fp32 -> bf16 hi + lo) ----------------
__global__ __launch_bounds__(256) void split_pair(const float4* __restrict__ x,
                                                  u16* __restrict__ hi, u16* __restrict__ lo) {
  const size_t i = (size_t)blockIdx.x * 256 + threadIdx.x;
  const float4 v = x[i];
  ushort4 h, l;
  h.x = f2bf(v.x); l.x = f2bf(v.x - bf2f(h.x));
  h.y = f2bf(v.y); l.y = f2bf(v.y - bf2f(h.y));
  h.z = f2bf(v.z); l.z = f2bf(v.z - bf2f(h.z));
  h.w = f2bf(v.w); l.w = f2bf(v.w - bf2f(h.w));
  *(ushort4*)&hi[i * 4] = h;
  *(ushort4*)&lo[i * 4] = l;
}

// ------------- transpose + split W (fp32 [K][N] -> bf16 [N][K] hi(,lo)) -------------
template<bool LO>
__global__ __launch_bounds__(256) void transpose_split(const float* __restrict__ W,
                                                       u16* __restrict__ Th, u16* __restrict__ Tl) {
  __shared__ float t[64][65];
  const int r0 = blockIdx.y * 64, c0 = blockIdx.x * 64;
  const int rr = threadIdx.x >> 4, c4 = (threadIdx.x & 15) * 4;
#pragma unroll
  for (int p = 0; p < 4; ++p) {
    const float4 v = *(const float4*)&W[(size_t)(r0 + p * 16 + rr) * 2048 + c0 + c4];
    t[p * 16 + rr][c4 + 0] = v.x; t[p * 16 + rr][c4 + 1] = v.y;
    t[p * 16 + rr][c4 + 2] = v.z; t[p * 16 + rr][c4 + 3] = v.w;
  }
  __syncthreads();
#pragma unroll
  for (int p = 0; p < 4; ++p) {
    const int cc = p * 16 + rr;
    const float v0 = t[c4 + 0][cc], v1 = t[c4 + 1][cc], v2 = t[c4 + 2][cc], v3 = t[c4 + 3][cc];
    ushort4 h;
    h.x = f2bf(v0); h.y = f2bf(v1); h.z = f2bf(v2); h.w = f2bf(v3);
    *(ushort4*)&Th[(size_t)(c0 + cc) * 2048 + r0 + c4] = h;
    if constexpr (LO) {
      ushort4 l;
      l.x = f2bf(v0 - bf2f(h.x)); l.y = f2bf(v1 - bf2f(h.y));
      l.z = f2bf(v2 - bf2f(h.z)); l.w = f2bf(v3 - bf2f(h.w));
      *(ushort4*)&Tl[(size_t)(c0 + cc) * 2048 + r0 + c4] = l;
    }
  }
}

// ---------------- GEMM: C[M,N] = A[M,K] @ Bt[N,K]^T  (m97-style 128x128 tile) ----------------
// SPLIT3: A,B given as hi/lo pairs, compute AhBh + AhBl + AlBh (split-bf16 fp32 emulation).
// OUTMODE: 0 = write C as bf16 hi+lo pair; 1 = bf16; 2 = bf16 transposed into Vt[b][n][m%2048]; 3 = fp32.
template<bool SPLIT3, int OUTMODE>
__global__ __launch_bounds__(256, 2) void gemm_bt(
    const u16* __restrict__ Aph, const u16* __restrict__ Apl,
    const u16* __restrict__ Bph, const u16* __restrict__ Bpl,
    void* __restrict__ C0, void* __restrict__ C1,
    const int M, const int N, const int K, const int bShift) {
  extern __shared__ u16 lds[];
  constexpr int T_AL = 4096;
  constexpr int T_BH = SPLIT3 ? 8192 : 4096;
  constexpr int T_BL = 12288;
  const int tid = threadIdx.x;
  const int wave = tid >> 6, lane = tid & 63;
  const int li = lane & 15, l4 = lane >> 4;
  const int m0 = blockIdx.y * 128, n0 = blockIdx.x * 128;
  const int wr = (wave >> 1) * 64, wc = (wave & 1) * 64;
  const u16* Bh = Bph; const u16* Bl = Bpl;
  if (bShift) { const size_t s = (size_t)(m0 >> 11) * (size_t)bShift; Bh += s; if (SPLIT3) Bl += s; }

  const f32x4 fz = {0.f, 0.f, 0.f, 0.f};
  f32x4 acc[4][4];
#pragma unroll
  for (int m = 0; m < 4; ++m)
#pragma unroll
    for (int n = 0; n < 4; ++n) acc[m][n] = fz;

  const size_t aoff = (size_t)(m0 + (tid >> 2)) * K + (tid & 3) * 8;
  const size_t boff = (size_t)(n0 + (tid >> 2)) * K + (tid & 3) * 8;
  const size_t rstep = (size_t)64 * K;
  const int s0 = tid * 8, s1 = 2048 + tid * 8;
  const int abase = (wr + li) * 32 + l4 * 8;
  const int bbase = (wc + li) * 32 + l4 * 8;

#pragma unroll 1
  for (int k0 = 0; k0 < K; k0 += 32) {
    cp16(Aph + aoff + k0,         &lds[s0]);
    cp16(Aph + aoff + rstep + k0, &lds[s1]);
    cp16(Bh + boff + k0,          &lds[T_BH + s0]);
    cp16(Bh + boff + rstep + k0,  &lds[T_BH + s1]);
    if constexpr (SPLIT3) {
      cp16(Apl + aoff + k0,         &lds[T_AL + s0]);
      cp16(Apl + aoff + rstep + k0, &lds[T_AL + s1]);
      cp16(Bl + boff + k0,          &lds[T_BL + s0]);
      cp16(Bl + boff + rstep + k0,  &lds[T_BL + s1]);
    }
    __syncthreads();
    bf16x8 af[4], bf_[4];
#pragma unroll
    for (int m = 0; m < 4; ++m) af[m] = *(const bf16x8*)&lds[abase + m * 512];
#pragma unroll
    for (int n = 0; n < 4; ++n) bf_[n] = *(const bf16x8*)&lds[T_BH + bbase + n * 512];
    if constexpr (SPLIT3) {
      bf16x8 alf[4], blf[4];
#pragma unroll
      for (int m = 0; m < 4; ++m) alf[m] = *(const bf16x8*)&lds[T_AL + abase + m * 512];
#pragma unroll
      for (int n = 0; n < 4; ++n) blf[n] = *(const bf16x8*)&lds[T_BL + bbase + n * 512];
#pragma unroll
      for (int m = 0; m < 4; ++m)
#pragma unroll
        for (int n = 0; n < 4; ++n) {
          acc[m][n] = mfma16(af[m], bf_[n], acc[m][n]);
          acc[m][n] = mfma16(af[m], blf[n], acc[m][n]);
          acc[m][n] = mfma16(alf[m], bf_[n], acc[m][n]);
        }
    } else {
#pragma unroll
      for (int m = 0; m < 4; ++m)
#pragma unroll
        for (int n = 0; n < 4; ++n)
          acc[m][n] = mfma16(af[m], bf_[n], acc[m][n]);
    }
    __syncthreads();
  }

#pragma unroll
  for (int m = 0; m < 4; ++m) {
#pragma unroll
    for (int n = 0; n < 4; ++n) {
      const int rg0 = m0 + wr + m * 16 + l4 * 4;   // C/D layout: row=(lane>>4)*4+r
      const int cg  = n0 + wc + n * 16 + li;       //             col=lane&15
      if constexpr (OUTMODE == 0) {
        u16* Ch = (u16*)C0; u16* Cl = (u16*)C1;
#pragma unroll
        for (int r = 0; r < 4; ++r) {
          const float v = acc[m][n][r];
          const u16 h = f2bf(v);
          Ch[(size_t)(rg0 + r) * N + cg] = h;
          Cl[(size_t)(rg0 + r) * N + cg] = f2bf(v - bf2f(h));
        }
      } else if constexpr (OUTMODE == 1) {
        u16* Cs = (u16*)C0;
#pragma unroll
        for (int r = 0; r < 4; ++r) Cs[(size_t)(rg0 + r) * N + cg] = f2bf(acc[m][n][r]);
      } else if constexpr (OUTMODE == 2) {
        u16* Vt = (u16*)C0;   // Vt[b][d][s], rows rg0..rg0+3 are contiguous s
        ushort4 pk;
        pk.x = f2bf(acc[m][n][0]); pk.y = f2bf(acc[m][n][1]);
        pk.z = f2bf(acc[m][n][2]); pk.w = f2bf(acc[m][n][3]);
        *(ushort4*)&Vt[(size_t)(rg0 >> 11) * 4194304 + (size_t)cg * 2048 + (rg0 & 2047)] = pk;
      } else {
        float* Cf = (float*)C0;
#pragma unroll
        for (int r = 0; r < 4; ++r) Cf[(size_t)(rg0 + r) * N + cg] = acc[m][n][r];
      }
    }
  }
}

// ---------------- attention: Psum[b,q,k] = sum_h softmax_h((QK^T masked)*SCALE) ----------------
// block = (qb, b): 16 q-rows, 512 threads (8 waves), wave w owns keys [w*256, w*256+256).
// Scores for full row kept in registers (16 x f32x4 per lane); Psum accumulated in registers.
__global__ __launch_bounds__(512, 2) void attn_kernel(
    const u16* __restrict__ Qh, const u16* __restrict__ Ql,
    const u16* __restrict__ Kh, const u16* __restrict__ Kl,
    u16* __restrict__ Psum) {
  const int b = blockIdx.y, qb = blockIdx.x;
  const int tid = threadIdx.x, wave = tid >> 6, lane = tid & 63;
  const int li = lane & 15, l4 = lane >> 4;
  const int k0w = wave * 256;
  const int q0 = qb * 16;
  __shared__ float red[8][16];
  __shared__ float fm[16];
  __shared__ float fs[16];
  const f32x4 fz = {0.f, 0.f, 0.f, 0.f};
  f32x4 ps[16];
#pragma unroll
  for (int nt = 0; nt < 16; ++nt) ps[nt] = fz;
  const float cexp = 0.08838834764831845f * 1.4426950408889634f;  // SCALE * log2(e)

#pragma unroll 1
  for (int h = 0; h < 16; ++h) {
    const size_t qoff = ((size_t)(b * 2048 + q0 + li)) * 2048 + h * 128 + l4 * 8;
    bf16x8 qfh[4], qfl[4];
#pragma unroll
    for (int ks = 0; ks < 4; ++ks) {
      qfh[ks] = *(const bf16x8*)&Qh[qoff + ks * 32];
      qfl[ks] = *(const bf16x8*)&Ql[qoff + ks * 32];
    }
    const size_t koff0 = ((size_t)(b * 2048 + k0w + li)) * 2048 + h * 128 + l4 * 8;
    f32x4 sc[16];
#pragma unroll
    for (int nt = 0; nt < 16; ++nt) {
      f32x4 a = fz;
      const size_t ko = koff0 + (size_t)nt * 16 * 2048;
#pragma unroll
      for (int ks = 0; ks < 4; ++ks) {
        const bf16x8 kfh = *(const bf16x8*)&Kh[ko + ks * 32];
        const bf16x8 kfl = *(const bf16x8*)&Kl[ko + ks * 32];
        a = mfma16(qfh[ks], kfh, a);
        a = mfma16(qfh[ks], kfl, a);
        a = mfma16(qfl[ks], kfh, a);
      }
      sc[nt] = a;
    }
    // masked row max (raw scores; scale is positive so max commutes)
    float rmax[4];
#pragma unroll
    for (int r = 0; r < 4; ++r) rmax[r] = -3.0e38f;
#pragma unroll
    for (int nt = 0; nt < 16; ++nt) {
      const int kg = k0w + nt * 16 + li;
#pragma unroll
      for (int r = 0; r < 4; ++r) {
        const int qg = q0 + l4 * 4 + r;
        if (kg <= qg) rmax[r] = fmaxf(rmax[r], sc[nt][r]);
      }
    }
#pragma unroll
    for (int off = 8; off >= 1; off >>= 1)
#pragma unroll
      for (int r = 0; r < 4; ++r) rmax[r] = fmaxf(rmax[r], __shfl_xor(rmax[r], off, 64));
    if (li == 0) {
#pragma unroll
      for (int r = 0; r < 4; ++r) red[wave][l4 * 4 + r] = rmax[r];
    }
    __syncthreads();
    if (tid < 16) {
      float m = red[0][tid];
#pragma unroll
      for (int w = 1; w < 8; ++w) m = fmaxf(m, red[w][tid]);
      fm[tid] = m;
    }
    __syncthreads();
    float mrow[4], rsum[4];
#pragma unroll
    for (int r = 0; r < 4; ++r) { mrow[r] = fm[l4 * 4 + r]; rsum[r] = 0.f; }
#pragma unroll
    for (int nt = 0; nt < 16; ++nt) {
      const int kg = k0w + nt * 16 + li;
#pragma unroll
      for (int r = 0; r < 4; ++r) {
        const int qg = q0 + l4 * 4 + r;
        float p = 0.f;
        if (kg <= qg) p = exp2f((sc[nt][r] - mrow[r]) * cexp);
        sc[nt][r] = p;
        rsum[r] += p;
      }
    }
#pragma unroll
    for (int off = 8; off >= 1; off >>= 1)
#pragma unroll
      for (int r = 0; r < 4; ++r) rsum[r] += __shfl_xor(rsum[r], off, 64);
    if (li == 0) {
#pragma unroll
      for (int r = 0; r < 4; ++r) red[wave][l4 * 4 + r] = rsum[r];
    }
    __syncthreads();
    if (tid < 16) {
      float s = red[0][tid];
#pragma unroll
      for (int w = 1; w < 8; ++w) s += red[w][tid];
      fs[tid] = 1.0f / s;
    }
    __syncthreads();
    float rrcp[4];
#pragma unroll
    for (int r = 0; r < 4; ++r) rrcp[r] = fs[l4 * 4 + r];
#pragma unroll
    for (int nt = 0; nt < 16; ++nt)
#pragma unroll
      for (int r = 0; r < 4; ++r) ps[nt][r] += sc[nt][r] * rrcp[r];
  }
  // write Psum (bf16)
#pragma unroll
  for (int nt = 0; nt < 16; ++nt) {
    const size_t o0 = ((size_t)(b * 2048 + q0 + l4 * 4)) * 2048 + k0w + nt * 16 + li;
#pragma unroll
    for (int r = 0; r < 4; ++r) Psum[o0 + (size_t)r * 2048] = f2bf(ps[nt][r]);
  }
}

// ---------------- launch ----------------
extern "C" void kernel_launch(void* const* d_in, const int* in_sizes, int n_in,
                              void* d_out, int out_size, void* d_ws, size_t ws_size,
                              hipStream_t stream) {
  (void)in_sizes; (void)n_in; (void)out_size; (void)ws_size;
  const float* x  = (const float*)d_in[0];
  const float* Wq = (const float*)d_in[1];
  const float* Wk = (const float*)d_in[2];
  const float* Wv = (const float*)d_in[3];
  const float* Wo = (const float*)d_in[4];
  u16* ws = (u16*)d_ws;
  const size_t E8 = 8388608, E4 = 4194304;
  u16* xh = ws;                // 8M u16 each
  u16* xl = ws + E8;
  u16* Qh = ws + 2 * E8;
  u16* Ql = ws + 3 * E8;
  u16* Kh = ws + 4 * E8;
  u16* Kl = ws + 5 * E8;
  u16* Vt = ws + 6 * E8;       // [b][d][s]
  u16* WTh = ws + 7 * E8;      // reused: Wq then Wk
  u16* WTl = ws + 7 * E8 + E4;
  u16* WTb = ws + 7 * E8 + 2 * E4;  // reused: Wv then Wo
  u16* Psum = xl;              // x splits dead after projections
  u16* out1 = xh;
  // total ws use: 7*E8 + 3*E4 = 71,303,168 u16 = 136 MiB

  // x is 2*2048*2048 = 8,388,608 floats = 2,097,152 float4 -> 8192 blocks of 256
  split_pair<<<8192, 256, 0, stream>>>((const float4*)x, xh, xl);

  dim3 tg(32, 32);
  dim3 gg(16, 32);

  transpose_split<true ><<<tg, 256, 0, stream>>>(Wq, WTh, WTl);
  gemm_bt<true, 0><<<gg, 256, 32768, stream>>>(xh, xl, WTh, WTl, Qh, Ql, 4096, 2048, 2048, 0);

  transpose_split<true ><<<tg, 256, 0, stream>>>(Wk, WTh, WTl);
  gemm_bt<true, 0><<<gg, 256, 32768, stream>>>(xh, xl, WTh, WTl, Kh, Kl, 4096, 2048, 2048, 0);

  transpose_split<false><<<tg, 256, 0, stream>>>(Wv, WTb, nullptr);
  gemm_bt<false, 2><<<gg, 256, 16384, stream>>>(xh, nullptr, WTb, nullptr, Vt, nullptr, 4096, 2048, 2048, 0);

  attn_kernel<<<dim3(128, 2), 512, 0, stream>>>(Qh, Ql, Kh, Kl, Psum);

  gemm_bt<false, 1><<<gg, 256, 16384, stream>>>(Psum, nullptr, Vt, nullptr, out1, nullptr, 4096, 2048, 2048, 4194304);

  transpose_split<false><<<tg, 256, 0, stream>>>(Wo, WTb, nullptr);
  gemm_bt<false, 3><<<gg, 256, 16384, stream>>>(out1, nullptr, WTb, nullptr, d_out, nullptr, 4096, 2048, 2048, 0);
}